// Round 4
// baseline (96.284 us; speedup 1.0000x reference)
//
#include <hip/hip_runtime.h>
#include <hip/hip_bf16.h>
#include <hip/hip_fp16.h>

// Problem constants (fixed by reference)
#define NB     512
#define INF    1024
#define OUTF   64
#define PROJ   1024          // OUT_FEATURES * KERNEL_DIMS
#define OROW   (INF + OUTF)  // 1088

typedef short short8 __attribute__((ext_vector_type(8)));
typedef float floatx4 __attribute__((ext_vector_type(4)));

#define LDT 40   // LDS row stride in shorts: 80 B = 5*16B -> b128 frags aligned

__device__ __forceinline__ unsigned pack_bf16(float x, float y) {
    __hip_bfloat162 h = __float22bfloat162_rn(make_float2(x, y));  // v_cvt_pk_bf16_f32
    union { __hip_bfloat162 h; unsigned u; } v; v.h = h; return v.u;
}

__device__ __forceinline__ __half2 as_h2(unsigned u) {
    union { unsigned u; __half2 h; } v; v.u = u; return v.h;
}

// ---------------------------------------------------------------------------
// Kernel 1 (fused): M16 = half(x @ T) via bf16 MFMA, + copy x slice -> out,
// + init two o_b rows to -1 (absorbs the self-similarity diagonal).
// Tile 32M x 64N, BK=32, 256 thr (4 waves; wave w: m-half w&1, n-half w>>1,
// 2 MFMA tiles each). Grid (16 n, 16 m) = 256 blocks -> 1/CU.
// L2 traffic: A (PROJ/64)x2MB=32MB + B (NB/32)x4MB=64MB = 96 MB (~2.8 us).
// Register prefetch of iter k+1 issued before MFMA(k) hides load latency.
// ---------------------------------------------------------------------------
__global__ __launch_bounds__(256, 2) void gemm_fused(const float* __restrict__ A,
                                                     const float* __restrict__ B,
                                                     float* __restrict__ out,
                                                     __half* __restrict__ M16) {
    __shared__ short As[32 * LDT];
    __shared__ short Bs[64 * LDT];

    const int t    = threadIdx.x;
    const int lane = t & 63, w = t >> 6;
    const int bnx = blockIdx.x, bmy = blockIdx.y;
    const int bm = bmy * 32, bn = bnx * 64;

    // --- fused: copy x[bm..bm+32, bn..bn+64] -> out (2 float4 / thread) ---
    {
        const int r = t >> 3, c8 = (t & 7) * 8;
        *(float4*)&out[(size_t)(bm + r) * OROW + bn + c8] =
            *(const float4*)&A[(size_t)(bm + r) * INF + bn + c8];
        *(float4*)&out[(size_t)(bm + r) * OROW + bn + c8 + 4] =
            *(const float4*)&A[(size_t)(bm + r) * INF + bn + c8 + 4];
    }
    // --- fused: out[row, 1024:1088] = -1 for 2 rows per block ---
    if (t < 32) {
        const int row = (bmy * 16 + bnx) * 2 + (t >> 4);
        *(float4*)&out[(size_t)row * OROW + INF + (t & 15) * 4] =
            make_float4(-1.f, -1.f, -1.f, -1.f);
    }

    // staging coords
    const int am = t >> 3,        ak  = (t & 7) * 4;   // A: 32 rows x 32 k, float4/thr
    const int bk = (t >> 4) * 2,  bn0 = (t & 15) * 4;  // B: 32 k x 64 n, 2 float4/thr

    // fragment pointers: frag[r16 = lane&15][k = (lane>>4)*8 + j]
    const int q = lane >> 4, c = lane & 15;
    const int mh = w & 1, nh = w >> 1;
    const short* ap  = &As[(mh * 16 + c) * LDT + q * 8];
    const short* bp0 = &Bs[(nh * 32 + c) * LDT + q * 8];
    const short* bp1 = bp0 + 16 * LDT;

    floatx4 acc0 = {0.f, 0.f, 0.f, 0.f};
    floatx4 acc1 = {0.f, 0.f, 0.f, 0.f};

    // prefetch k0 = 0
    float4 av  = *(const float4*)&A[(size_t)(bm + am) * INF + ak];
    float4 bv0 = *(const float4*)&B[(size_t)bk * PROJ + bn + bn0];
    float4 bv1 = *(const float4*)&B[(size_t)(bk + 1) * PROJ + bn + bn0];

    for (int k0 = 0; k0 < INF; k0 += 32) {
        __syncthreads();   // previous iteration's frag reads complete
        *(uint2*)&As[am * LDT + ak] =
            make_uint2(pack_bf16(av.x, av.y), pack_bf16(av.z, av.w));
        *(unsigned*)&Bs[(bn0 + 0) * LDT + bk] = pack_bf16(bv0.x, bv1.x);
        *(unsigned*)&Bs[(bn0 + 1) * LDT + bk] = pack_bf16(bv0.y, bv1.y);
        *(unsigned*)&Bs[(bn0 + 2) * LDT + bk] = pack_bf16(bv0.z, bv1.z);
        *(unsigned*)&Bs[(bn0 + 3) * LDT + bk] = pack_bf16(bv0.w, bv1.w);
        __syncthreads();

        const int kn = k0 + 32;
        if (kn < INF) {    // next-iteration loads stay in flight during MFMA
            av  = *(const float4*)&A[(size_t)(bm + am) * INF + kn + ak];
            bv0 = *(const float4*)&B[(size_t)(kn + bk) * PROJ + bn + bn0];
            bv1 = *(const float4*)&B[(size_t)(kn + bk + 1) * PROJ + bn + bn0];
        }

        const short8 af  = *(const short8*)ap;
        const short8 bf0 = *(const short8*)bp0;
        const short8 bf1 = *(const short8*)bp1;
        acc0 = __builtin_amdgcn_mfma_f32_16x16x32_bf16(af, bf0, acc0, 0, 0, 0);
        acc1 = __builtin_amdgcn_mfma_f32_16x16x32_bf16(af, bf1, acc1, 0, 0, 0);
    }

    // epilogue: C/D layout col=lane&15, row=(lane>>4)*4+r -> write fp16 M
#pragma unroll
    for (int r = 0; r < 4; ++r) {
        const int row = bm + mh * 16 + q * 4 + r;
        M16[(size_t)row * PROJ + bn + nh * 32 + c]      = __float2half(acc0[r]);
        M16[(size_t)row * PROJ + bn + nh * 32 + 16 + c] = __float2half(acc1[r]);
    }
}

// ---------------------------------------------------------------------------
// Kernel 2: pairwise L1 (packed fp16) + exp + sum over one 64-row j-slice,
// atomic accumulate into out[:, 1024:1088].
// Block = 32 i x 4 o (128 thr); grid (og 16, ig 16, js 8) = 2048 blocks.
// LDS 8 KB -> 8+ blocks/CU resident, 16 waves/CU.
// Skip-exp: norms are ~576 +- 108, so norm<24 is ~never true; the wave-uniform
// branch skips the cvt/exp/add tail. Skipped terms < e^-24 * 511 < 2e-8.
// ---------------------------------------------------------------------------
__global__ __launch_bounds__(128) void pairwise_h2(const __half* __restrict__ M16,
                                                   float* __restrict__ out) {
    __shared__ __half Mj[64 * 64];

    const int t  = threadIdx.x;
    const int o  = t & 3;
    const int il = t >> 2;
    const int og = blockIdx.x;
    const int ig = blockIdx.y;
    const int j0 = blockIdx.z * 64;
    const int i  = ig * 32 + il;

    // my i-row fragment: 16 halves = 32 B
    const uint4* mp = (const uint4*)&M16[(size_t)i * PROJ + og * 64 + o * 16];
    const uint4 a0 = mp[0], a1 = mp[1];

    // stage 64 j-rows x 64 halves (8 KB): 128 thr x 4 x 16 B
#pragma unroll
    for (int cc = 0; cc < 4; ++cc) {
        const int idx = (cc * 128 + t) * 8;  // half index
        const int jl  = idx >> 6;
        const int col = idx & 63;
        *(uint4*)&Mj[jl * 64 + col] =
            *(const uint4*)&M16[(size_t)(j0 + jl) * PROJ + og * 64 + col];
    }
    __syncthreads();

    float sum = 0.f;
#pragma unroll 8
    for (int jl = 0; jl < 64; ++jl) {
        const uint4 b0 = *(const uint4*)&Mj[jl * 64 + o * 16];
        const uint4 b1 = *(const uint4*)&Mj[jl * 64 + o * 16 + 8];
        __half2 s0 = __hadd2(__habs2(__hsub2(as_h2(a0.x), as_h2(b0.x))),
                             __habs2(__hsub2(as_h2(a0.y), as_h2(b0.y))));
        __half2 s1 = __hadd2(__habs2(__hsub2(as_h2(a0.z), as_h2(b0.z))),
                             __habs2(__hsub2(as_h2(a0.w), as_h2(b0.w))));
        __half2 s2 = __hadd2(__habs2(__hsub2(as_h2(a1.x), as_h2(b1.x))),
                             __habs2(__hsub2(as_h2(a1.y), as_h2(b1.y))));
        __half2 s3 = __hadd2(__habs2(__hsub2(as_h2(a1.z), as_h2(b1.z))),
                             __habs2(__hsub2(as_h2(a1.w), as_h2(b1.w))));
        const __half2 s = __hadd2(__hadd2(s0, s1), __hadd2(s2, s3));
        const float norm = __low2float(s) + __high2float(s);
        if (norm < 24.f)           // wave-uniform in practice: skip exp tail
            sum += __expf(-norm);
    }

    __hip_atomic_fetch_add(&out[(size_t)i * OROW + INF + og * 4 + o],
                           sum, __ATOMIC_RELAXED, __HIP_MEMORY_SCOPE_AGENT);
}

extern "C" void kernel_launch(void* const* d_in, const int* in_sizes, int n_in,
                              void* d_out, int out_size, void* d_ws, size_t ws_size,
                              hipStream_t stream) {
    const float* x = (const float*)d_in[0];   // [512,1024] fp32
    const float* T = (const float*)d_in[1];   // [1024,1024] fp32
    float* out  = (float*)d_out;              // [512,1088] fp32
    __half* M16 = (__half*)d_ws;              // [512,1024] fp16 scratch (1 MB)

    gemm_fused<<<dim3(PROJ / 64, NB / 32), 256, 0, stream>>>(x, T, out, M16);
    pairwise_h2<<<dim3(OUTF / 4, NB / 32, NB / 64), 128, 0, stream>>>(M16, out);
}

// Round 5
// 92.966 us; speedup vs baseline: 1.0357x; 1.0357x over previous
//
#include <hip/hip_runtime.h>
#include <hip/hip_bf16.h>
#include <hip/hip_fp16.h>

// Problem constants (fixed by reference)
#define NB     512
#define INF    1024
#define OUTF   64
#define PROJ   1024          // OUT_FEATURES * KERNEL_DIMS
#define OROW   (INF + OUTF)  // 1088

typedef short short8 __attribute__((ext_vector_type(8)));
typedef float floatx4 __attribute__((ext_vector_type(4)));

#define LDT 40   // LDS row stride in shorts: 80 B = 5*16B -> b128 frags aligned

__device__ __forceinline__ unsigned pack_bf16(float x, float y) {
    __hip_bfloat162 h = __float22bfloat162_rn(make_float2(x, y));  // v_cvt_pk_bf16_f32
    union { __hip_bfloat162 h; unsigned u; } v; v.h = h; return v.u;
}

__device__ __forceinline__ __half2 as_h2(unsigned u) {
    union { unsigned u; __half2 h; } v; v.u = u; return v.h;
}

// ---------------------------------------------------------------------------
// Kernel 1 (fused): M16 = half(x @ T) via bf16 MFMA, + copy x slice -> out,
// + init one o_b row to -1 (absorbs the self-similarity diagonal).
// Tile 16M x 64N, BK=32, 256 thr (4 waves, one 16x16 n-quarter each).
// Grid (16 n, 32 m) = 512 blocks -> 2 blocks/CU, 8 waves/CU.  [R3 measured
// best: the 32M tile (R4) cut L2 traffic but halved occupancy -> +3.4 us.]
// Register prefetch of iter k+1 issued before MFMA(k) hides load latency.
// ---------------------------------------------------------------------------
__global__ __launch_bounds__(256, 2) void gemm_fused(const float* __restrict__ A,
                                                     const float* __restrict__ B,
                                                     float* __restrict__ out,
                                                     __half* __restrict__ M16) {
    __shared__ short As[16 * LDT];
    __shared__ short Bs[64 * LDT];

    const int t    = threadIdx.x;
    const int lane = t & 63, w = t >> 6;
    const int bnx = blockIdx.x, bmy = blockIdx.y;
    const int bm = bmy * 16, bn = bnx * 64;

    // --- fused: copy x[bm..bm+16, bn..bn+64] -> out (16 rows x 64 cols) ---
    {
        const int r = t >> 4, c4 = (t & 15) * 4;
        *(float4*)&out[(size_t)(bm + r) * OROW + bn + c4] =
            *(const float4*)&A[(size_t)(bm + r) * INF + bn + c4];
    }
    // --- fused: out[row, 1024:1088] = -1 for row = linear block id (0..511) ---
    if (t < 16) {
        const int row = bmy * 16 + bnx;
        *(float4*)&out[(size_t)row * OROW + INF + t * 4] =
            make_float4(-1.f, -1.f, -1.f, -1.f);
    }

    // staging coords
    const int am = t >> 4,        ak  = (t & 15) * 2;  // A: 16 rows x 32 k
    const int bk = (t >> 4) * 2,  bn0 = (t & 15) * 4;  // B: 32 k x 64 n

    // fragment pointers: frag[r16 = lane&15][k = (lane>>4)*8 + j]
    const int q = lane >> 4, c = lane & 15;
    const short* ap = &As[c * LDT + q * 8];
    const short* bp = &Bs[(w * 16 + c) * LDT + q * 8];

    floatx4 acc = {0.f, 0.f, 0.f, 0.f};

    // prefetch k0 = 0
    float2 av  = *(const float2*)&A[(size_t)(bm + am) * INF + ak];
    float4 bv0 = *(const float4*)&B[(size_t)bk * PROJ + bn + bn0];
    float4 bv1 = *(const float4*)&B[(size_t)(bk + 1) * PROJ + bn + bn0];

    for (int k0 = 0; k0 < INF; k0 += 32) {
        __syncthreads();   // previous iteration's frag reads complete
        *(unsigned*)&As[am * LDT + ak]        = pack_bf16(av.x, av.y);
        *(unsigned*)&Bs[(bn0 + 0) * LDT + bk] = pack_bf16(bv0.x, bv1.x);
        *(unsigned*)&Bs[(bn0 + 1) * LDT + bk] = pack_bf16(bv0.y, bv1.y);
        *(unsigned*)&Bs[(bn0 + 2) * LDT + bk] = pack_bf16(bv0.z, bv1.z);
        *(unsigned*)&Bs[(bn0 + 3) * LDT + bk] = pack_bf16(bv0.w, bv1.w);
        __syncthreads();

        const int kn = k0 + 32;
        if (kn < INF) {    // next-iteration loads stay in flight during MFMA
            av  = *(const float2*)&A[(size_t)(bm + am) * INF + kn + ak];
            bv0 = *(const float4*)&B[(size_t)(kn + bk) * PROJ + bn + bn0];
            bv1 = *(const float4*)&B[(size_t)(kn + bk + 1) * PROJ + bn + bn0];
        }

        const short8 af = *(const short8*)ap;
        const short8 bf = *(const short8*)bp;
        acc = __builtin_amdgcn_mfma_f32_16x16x32_bf16(af, bf, acc, 0, 0, 0);
    }

    // epilogue: C/D layout col=lane&15, row=(lane>>4)*4+r -> write fp16 M
#pragma unroll
    for (int r = 0; r < 4; ++r) {
        M16[(size_t)(bm + q * 4 + r) * PROJ + bn + w * 16 + c] = __float2half(acc[r]);
    }
}

// ---------------------------------------------------------------------------
// Kernel 2: pairwise L1 (packed fp16) + exp + sum over one 64-row j-slice,
// atomic accumulate into out[:, 1024:1088].
// Block = 32 i x 4 o (128 thr); grid (og 16, ig 16, js 8) = 2048 blocks.
// LDS 8 KB -> 16 waves/CU resident.
// Skip-exp: norms are ~576 +- 108, so norm<24 is ~never true; the wave-uniform
// branch skips the cvt/exp/add tail. Skipped terms < e^-24 * 511 < 2e-8.
// ---------------------------------------------------------------------------
__global__ __launch_bounds__(128) void pairwise_h2(const __half* __restrict__ M16,
                                                   float* __restrict__ out) {
    __shared__ __half Mj[64 * 64];

    const int t  = threadIdx.x;
    const int o  = t & 3;
    const int il = t >> 2;
    const int og = blockIdx.x;
    const int ig = blockIdx.y;
    const int j0 = blockIdx.z * 64;
    const int i  = ig * 32 + il;

    // my i-row fragment: 16 halves = 32 B
    const uint4* mp = (const uint4*)&M16[(size_t)i * PROJ + og * 64 + o * 16];
    const uint4 a0 = mp[0], a1 = mp[1];

    // stage 64 j-rows x 64 halves (8 KB): 128 thr x 4 x 16 B
#pragma unroll
    for (int cc = 0; cc < 4; ++cc) {
        const int idx = (cc * 128 + t) * 8;  // half index
        const int jl  = idx >> 6;
        const int col = idx & 63;
        *(uint4*)&Mj[jl * 64 + col] =
            *(const uint4*)&M16[(size_t)(j0 + jl) * PROJ + og * 64 + col];
    }
    __syncthreads();

    float sum = 0.f;
#pragma unroll 8
    for (int jl = 0; jl < 64; ++jl) {
        const uint4 b0 = *(const uint4*)&Mj[jl * 64 + o * 16];
        const uint4 b1 = *(const uint4*)&Mj[jl * 64 + o * 16 + 8];
        __half2 s0 = __hadd2(__habs2(__hsub2(as_h2(a0.x), as_h2(b0.x))),
                             __habs2(__hsub2(as_h2(a0.y), as_h2(b0.y))));
        __half2 s1 = __hadd2(__habs2(__hsub2(as_h2(a0.z), as_h2(b0.z))),
                             __habs2(__hsub2(as_h2(a0.w), as_h2(b0.w))));
        __half2 s2 = __hadd2(__habs2(__hsub2(as_h2(a1.x), as_h2(b1.x))),
                             __habs2(__hsub2(as_h2(a1.y), as_h2(b1.y))));
        __half2 s3 = __hadd2(__habs2(__hsub2(as_h2(a1.z), as_h2(b1.z))),
                             __habs2(__hsub2(as_h2(a1.w), as_h2(b1.w))));
        const __half2 s = __hadd2(__hadd2(s0, s1), __hadd2(s2, s3));
        const float norm = __low2float(s) + __high2float(s);
        if (norm < 24.f)           // wave-uniform in practice: skip exp tail
            sum += __expf(-norm);
    }

    __hip_atomic_fetch_add(&out[(size_t)i * OROW + INF + og * 4 + o],
                           sum, __ATOMIC_RELAXED, __HIP_MEMORY_SCOPE_AGENT);
}

extern "C" void kernel_launch(void* const* d_in, const int* in_sizes, int n_in,
                              void* d_out, int out_size, void* d_ws, size_t ws_size,
                              hipStream_t stream) {
    const float* x = (const float*)d_in[0];   // [512,1024] fp32
    const float* T = (const float*)d_in[1];   // [1024,1024] fp32
    float* out  = (float*)d_out;              // [512,1088] fp32
    __half* M16 = (__half*)d_ws;              // [512,1024] fp16 scratch (1 MB)

    gemm_fused<<<dim3(PROJ / 64, NB / 16), 256, 0, stream>>>(x, T, out, M16);
    pairwise_h2<<<dim3(OUTF / 4, NB / 32, NB / 64), 128, 0, stream>>>(M16, out);
}